// Round 9
// baseline (105.198 us; speedup 1.0000x reference)
//
#include <hip/hip_runtime.h>

#define N_NODES 50000
#define N_EDGES 800000
#define DIM 128
#define M_PAD 50048                 // row pad: 1564 fused blocks * 32 rows

#define BNODES 64                   // nodes per bucket (dst>>6)
#define NBUCK 782                   // ceil(N_NODES / 64)
#define SLACK 1280                  // per-bucket capacity (mean 1023, sigma 32)
#define EPB   4096                  // edges per binA block
#define NBLKA ((N_EDGES + EPB - 1) / EPB)   // 196
#define SPLIT 2                     // gather blocks per bucket

#define M_TILE 32                   // fused: rows per block
#define MW 2                        // fused: 16-row m-frags per wave

typedef __attribute__((ext_vector_type(8))) short bf16x8;
typedef __attribute__((ext_vector_type(4))) float f32x4;
typedef __attribute__((ext_vector_type(2))) float f32x2;   // native vec for NT store

// ws layout (bytes):
//   int gcur[1024]                    @ 0            (4,096)
//   u32 buf[NBUCK*SLACK]              @ 4,096        (4,003,840)
//   bf16 xh[M_PAD][128]               @ 4,007,936    (12,812,288)
//   bf16 WhT[128][256]                @ 16,820,224   (65,536)   -> total 16.9 MB
#define WS_BUF_OFF 4096
#define WS_XH_OFF  (WS_BUF_OFF + (size_t)NBUCK * SLACK * 4)
#define WS_WT_OFF  (WS_XH_OFF + (size_t)M_PAD * DIM * 2)

static __device__ __forceinline__ unsigned short f2b(float f) {
    unsigned int x = __float_as_uint(f);
    x += 0x7fffu + ((x >> 16) & 1u);
    return (unsigned short)(x >> 16);
}
static __device__ __forceinline__ float blo(unsigned int v) {
    return __uint_as_float(v << 16);
}
static __device__ __forceinline__ float bhi(unsigned int v) {
    return __uint_as_float(v & 0xffff0000u);
}

// ---------------- prep: cast x->bf16 + build WhT -------------------------------
#define CAST_BLOCKS 6250            // 6.4M floats / 4 / 256
#define WT_BLOCKS 64

__global__ __launch_bounds__(256) void prep_kernel(
    const float* __restrict__ x,
    const float* __restrict__ Wl,
    const float* __restrict__ Wr,
    unsigned short* __restrict__ xh,
    unsigned short* __restrict__ WhT)
{
    int b = blockIdx.x;
    int t = threadIdx.x;
    if (b < CAST_BLOCKS) {
        int i = b * 256 + t;
        float4 v = reinterpret_cast<const float4*>(x)[i];
        ushort4 h;
        h.x = f2b(v.x); h.y = f2b(v.y); h.z = f2b(v.z); h.w = f2b(v.w);
        reinterpret_cast<ushort4*>(xh)[i] = h;
    } else {
        int idx = (b - CAST_BLOCKS) * 256 + t;    // k*128+n over [128][128]
        int n = idx & 127;
        int k = idx >> 7;
        WhT[n * 256 + k]       = f2b(Wl[idx]);
        WhT[n * 256 + 128 + k] = f2b(Wr[idx]);
    }
}

// ---------------- binA: block-local counting sort into global bucket runs ------
__global__ __launch_bounds__(256) void binA_kernel(
    const int* __restrict__ src, const int* __restrict__ dst,
    int* __restrict__ gcur, unsigned int* __restrict__ buf)
{
    __shared__ unsigned int img[EPB];        // 16 KB block-sorted image
    __shared__ int hist[NBUCK];              // counts, then rank cursors
    __shared__ int lbase[NBUCK];             // exclusive prefix within block
    __shared__ int gbase[NBUCK];             // global target of this block's run
    const int tid = threadIdx.x;
    const int e0 = blockIdx.x * EPB;
    const int n = min(EPB, N_EDGES - e0);

    for (int i = tid; i < NBUCK; i += 256) hist[i] = 0;
    __syncthreads();
    for (int i = tid; i < n; i += 256)
        atomicAdd(&hist[dst[e0 + i] >> 6], 1);
    __syncthreads();
    // exclusive scan of hist[0..781]: wave 0, 13 values per lane
    if (tid < 64) {
        int c0 = tid * 13;
        int v[13];
        int s = 0;
        #pragma unroll
        for (int j = 0; j < 13; ++j) {
            int idx = c0 + j;
            v[j] = (idx < NBUCK) ? hist[idx] : 0;
            s += v[j];
        }
        int incl = s;
        #pragma unroll
        for (int d = 1; d < 64; d <<= 1) {
            int t = __shfl_up(incl, d, 64);
            if (tid >= d) incl += t;
        }
        int run = incl - s;
        #pragma unroll
        for (int j = 0; j < 13; ++j) {
            int idx = c0 + j;
            if (idx < NBUCK) lbase[idx] = run;
            run += v[j];
        }
    }
    __syncthreads();
    for (int i = tid; i < NBUCK; i += 256) {
        int c = hist[i];
        gbase[i] = i * SLACK + (c ? atomicAdd(&gcur[i], c) : 0);
        hist[i] = 0;                         // reuse as rank cursor
    }
    __syncthreads();
    for (int i = tid; i < n; i += 256) {
        int d = dst[e0 + i];
        int s = src[e0 + i];
        int b = d >> 6;
        int r = atomicAdd(&hist[b], 1);
        img[lbase[b] + r] = (unsigned int)s | ((unsigned int)d << 16);
    }
    __syncthreads();
    for (int i = tid; i < n; i += 256) {
        unsigned int v = img[i];
        int b = (int)(v >> 16) >> 6;
        int pos = gbase[b] + (i - lbase[b]);
        if (pos < (b + 1) * SLACK) buf[pos] = v;   // overflow drops, not corrupts
    }
}

// ---------------- binB: local CSR in LDS + gather-mean -------------------------
// SPLIT blocks per bucket: each rebuilds the bucket CSR (cheap) and gathers a
// 32-node slice. Per node: 16-deep clamped load batch, then clamped 8-batches.
__global__ __launch_bounds__(256) void binB_kernel(
    const unsigned int* __restrict__ buf,
    const int* __restrict__ gcur,
    const unsigned short* __restrict__ xh,
    float* __restrict__ agg)                 // d_out as [N_NODES][DIM] fp32
{
    __shared__ unsigned int ebuf[SLACK];     // 5,120 B packed edges
    __shared__ unsigned short csr[SLACK];    // 2,560 B local CSR (src u16)
    __shared__ int dhist[BNODES];            // per-node degree
    __shared__ int dbase[BNODES];            // per-node CSR offset
    __shared__ int dcur[BNODES];             // per-node rank cursor
    const int tid = threadIdx.x;
    const int b = blockIdx.x / SPLIT;        // bucket
    const int half = blockIdx.x % SPLIT;     // node slice
    const int cnt = min(gcur[b], SLACK);
    const unsigned int* bp = buf + (size_t)b * SLACK;

    if (tid < BNODES) { dhist[tid] = 0; dcur[tid] = 0; }
    for (int i = tid; i < cnt; i += 256) ebuf[i] = bp[i];
    __syncthreads();
    for (int i = tid; i < cnt; i += 256)
        atomicAdd(&dhist[(ebuf[i] >> 16) & 63], 1);
    __syncthreads();
    if (tid < 64) {                          // scan 64 degree values
        int v = dhist[tid];
        int incl = v;
        #pragma unroll
        for (int d = 1; d < 64; d <<= 1) {
            int t = __shfl_up(incl, d, 64);
            if (tid >= d) incl += t;
        }
        dbase[tid] = incl - v;
    }
    __syncthreads();
    for (int i = tid; i < cnt; i += 256) {
        unsigned int v = ebuf[i];
        int d = (v >> 16) & 63;
        int r = atomicAdd(&dcur[d], 1);
        csr[dbase[d] + r] = (unsigned short)(v & 0xFFFFu);
    }
    __syncthreads();

    // gather: wave w handles slice nodes half*32 + w + 4*j, j=0..7
    const int w = tid >> 6;
    const int lane = tid & 63;
    const unsigned int* xp = reinterpret_cast<const unsigned int*>(xh);
    for (int j = 0; j < 32 / 4; ++j) {
        int ln = half * 32 + w + 4 * j;
        int node = b * BNODES + ln;
        if (node >= N_NODES) break;
        int deg = dhist[ln];
        int start = dbase[ln];
        float ax = 0.f, ay = 0.f;
        if (deg > 0) {
            int dm1 = deg - 1;
            // 16-deep clamped batch (covers deg<=16 in one round trip)
            unsigned int v[16];
            #pragma unroll
            for (int t = 0; t < 16; ++t)
                v[t] = xp[csr[start + min(t, dm1)] * 64 + lane];
            #pragma unroll
            for (int t = 0; t < 16; ++t)
                if (t < deg) { ax += blo(v[t]); ay += bhi(v[t]); }
            // tail: clamped 8-batches
            for (int base = 16; base < deg; base += 8) {
                unsigned int u[8];
                #pragma unroll
                for (int t = 0; t < 8; ++t)
                    u[t] = xp[csr[start + min(base + t, dm1)] * 64 + lane];
                #pragma unroll
                for (int t = 0; t < 8; ++t)
                    if (base + t < deg) { ax += blo(u[t]); ay += bhi(u[t]); }
            }
        }
        float inv = 1.0f / (float)max(deg, 1);
        f32x2 o = {ax * inv, ay * inv};
        __builtin_nontemporal_store(
            o, reinterpret_cast<f32x2*>(agg + (size_t)node * DIM + lane * 2));
    }
}

// ---------------- fused MFMA GEMM + bias + LayerNorm + ReLU --------------------
// 32 rows x 128 cols per block (grid 1564 = 6 blocks/CU for latency hiding).
__global__ __launch_bounds__(256) void fused_kernel(
    const float* __restrict__ agg,
    const unsigned short* __restrict__ xh,
    const unsigned short* __restrict__ WhT,
    const float* __restrict__ bl,
    const float* __restrict__ gamma,
    const float* __restrict__ beta,
    float* __restrict__ out)
{
    __shared__ float sRed[M_TILE][4][2];
    const int tid = threadIdx.x;
    const int w = tid >> 6;
    const int l = tid & 63;
    const int r16 = l & 15;
    const int kg = l >> 4;
    const int rb = blockIdx.x * M_TILE;

    bf16x8 bf[2][8];
    #pragma unroll
    for (int f = 0; f < 2; ++f) {
        const unsigned short* wp = WhT + (w * 32 + f * 16 + r16) * 256 + kg * 8;
        #pragma unroll
        for (int kf = 0; kf < 8; ++kf)
            bf[f][kf] = *reinterpret_cast<const bf16x8*>(wp + kf * 32);
    }

    f32x4 acc[MW][2];
    #pragma unroll
    for (int m = 0; m < MW; ++m)
        #pragma unroll
        for (int f = 0; f < 2; ++f)
            acc[m][f] = (f32x4){0.f, 0.f, 0.f, 0.f};

    #pragma unroll
    for (int kf = 0; kf < 8; ++kf) {
        bf16x8 a[MW];
        if (kf < 4) {
            #pragma unroll
            for (int m = 0; m < MW; ++m) {
                int row = rb + m * 16 + r16;
                row = min(row, N_NODES - 1);
                const float* ap = agg + (size_t)row * DIM + kf * 32 + kg * 8;
                float4 u0 = *reinterpret_cast<const float4*>(ap);
                float4 u1 = *reinterpret_cast<const float4*>(ap + 4);
                bf16x8 t;
                t[0] = (short)f2b(u0.x); t[1] = (short)f2b(u0.y);
                t[2] = (short)f2b(u0.z); t[3] = (short)f2b(u0.w);
                t[4] = (short)f2b(u1.x); t[5] = (short)f2b(u1.y);
                t[6] = (short)f2b(u1.z); t[7] = (short)f2b(u1.w);
                a[m] = t;
            }
        } else {
            #pragma unroll
            for (int m = 0; m < MW; ++m) {
                int row = rb + m * 16 + r16;
                a[m] = *reinterpret_cast<const bf16x8*>(
                    xh + (size_t)row * DIM + (kf - 4) * 32 + kg * 8);
            }
        }
        #pragma unroll
        for (int m = 0; m < MW; ++m)
            #pragma unroll
            for (int f = 0; f < 2; ++f)
                acc[m][f] = __builtin_amdgcn_mfma_f32_16x16x32_bf16(
                    a[m], bf[f][kf], acc[m][f], 0, 0, 0);
    }

    float blv[2], gav[2], bev[2];
    #pragma unroll
    for (int f = 0; f < 2; ++f) {
        int col = w * 32 + f * 16 + r16;
        blv[f] = bl[col]; gav[f] = gamma[col]; bev[f] = beta[col];
    }
    #pragma unroll
    for (int m = 0; m < MW; ++m)
        #pragma unroll
        for (int r = 0; r < 4; ++r) {
            float v0 = acc[m][0][r] + blv[0];
            float v1 = acc[m][1][r] + blv[1];
            acc[m][0][r] = v0; acc[m][1][r] = v1;
            float s = v0 + v1;
            float q = v0 * v0 + v1 * v1;
            #pragma unroll
            for (int d = 1; d < 16; d <<= 1) {
                s += __shfl_xor(s, d, 16);
                q += __shfl_xor(q, d, 16);
            }
            if (r16 == 0) {
                sRed[m * 16 + kg * 4 + r][w][0] = s;
                sRed[m * 16 + kg * 4 + r][w][1] = q;
            }
        }
    __syncthreads();

    #pragma unroll
    for (int m = 0; m < MW; ++m)
        #pragma unroll
        for (int r = 0; r < 4; ++r) {
            int lr = m * 16 + kg * 4 + r;
            float S = sRed[lr][0][0] + sRed[lr][1][0] + sRed[lr][2][0] + sRed[lr][3][0];
            float Q = sRed[lr][0][1] + sRed[lr][1][1] + sRed[lr][2][1] + sRed[lr][3][1];
            float mean = S * (1.0f / 128.0f);
            float var = Q * (1.0f / 128.0f) - mean * mean;
            float rstd = rsqrtf(var + 1e-5f);
            int row = rb + lr;
            if (row < N_NODES) {
                #pragma unroll
                for (int f = 0; f < 2; ++f) {
                    float o = (acc[m][f][r] - mean) * rstd * gav[f] + bev[f];
                    out[(size_t)row * DIM + w * 32 + f * 16 + r16] = fmaxf(o, 0.f);
                }
            }
        }
}

extern "C" void kernel_launch(void* const* d_in, const int* in_sizes, int n_in,
                              void* d_out, int out_size, void* d_ws, size_t ws_size,
                              hipStream_t stream) {
    const float* x     = (const float*)d_in[0];
    const int*   ei    = (const int*)d_in[1];
    const float* Wl    = (const float*)d_in[2];
    const float* bl    = (const float*)d_in[3];
    const float* Wr    = (const float*)d_in[4];
    const float* gamma = (const float*)d_in[5];
    const float* beta  = (const float*)d_in[6];
    float* out = (float*)d_out;
    int*           gcur = (int*)d_ws;
    unsigned int*  buf  = (unsigned int*)((char*)d_ws + WS_BUF_OFF);
    unsigned short* xh  = (unsigned short*)((char*)d_ws + WS_XH_OFF);
    unsigned short* WhT = (unsigned short*)((char*)d_ws + WS_WT_OFF);

    const int* src = ei;
    const int* dst = ei + N_EDGES;

    (void)hipMemsetAsync(gcur, 0, 1024 * sizeof(int), stream);

    prep_kernel<<<CAST_BLOCKS + WT_BLOCKS, 256, 0, stream>>>(x, Wl, Wr, xh, WhT);
    binA_kernel<<<NBLKA, 256, 0, stream>>>(src, dst, gcur, buf);
    binB_kernel<<<NBUCK * SPLIT, 256, 0, stream>>>(buf, gcur, xh, out);
    fused_kernel<<<M_PAD / M_TILE, 256, 0, stream>>>(
        out, xh, WhT, bl, gamma, beta, out);
}

// Round 10
// 93.689 us; speedup vs baseline: 1.1228x; 1.1228x over previous
//
#include <hip/hip_runtime.h>

#define N_NODES 50000
#define N_EDGES 800000
#define DIM 128
#define M_PAD 50048                 // 1564 binBC blocks * 32 rows

#define BNODES 64                   // nodes per bucket (dst>>6)
#define NBUCK 782                   // ceil(N_NODES / 64)
#define SLACK 1280                  // per-bucket capacity (mean 1023, sigma 32)
#define EPB   4096                  // edges per binA block
#define NBLKA ((N_EDGES + EPB - 1) / EPB)   // 196
#define SPLIT 2                     // binBC blocks per bucket

#define M_TILE 32                   // binBC: rows per block
#define MW 2                        // binBC: 16-row m-frags per wave

typedef __attribute__((ext_vector_type(8))) short bf16x8;
typedef __attribute__((ext_vector_type(4))) float f32x4;

// ws layout (bytes):
//   int gcur[1024]                    @ 0            (4,096)
//   u32 buf[NBUCK*SLACK]              @ 4,096        (4,003,840)
//   bf16 xh[M_PAD][128]               @ 4,007,936    (12,812,288)
//   bf16 WhT[128][256]                @ 16,820,224   (65,536)   -> total 16.9 MB
#define WS_BUF_OFF 4096
#define WS_XH_OFF  (WS_BUF_OFF + (size_t)NBUCK * SLACK * 4)
#define WS_WT_OFF  (WS_XH_OFF + (size_t)M_PAD * DIM * 2)

static __device__ __forceinline__ unsigned short f2b(float f) {
    unsigned int x = __float_as_uint(f);
    x += 0x7fffu + ((x >> 16) & 1u);
    return (unsigned short)(x >> 16);
}
static __device__ __forceinline__ float blo(unsigned int v) {
    return __uint_as_float(v << 16);
}
static __device__ __forceinline__ float bhi(unsigned int v) {
    return __uint_as_float(v & 0xffff0000u);
}

// ---------------- prep: cast x->bf16 + build WhT -------------------------------
#define CAST_BLOCKS 6250            // 6.4M floats / 4 / 256
#define WT_BLOCKS 64

__global__ __launch_bounds__(256) void prep_kernel(
    const float* __restrict__ x,
    const float* __restrict__ Wl,
    const float* __restrict__ Wr,
    unsigned short* __restrict__ xh,
    unsigned short* __restrict__ WhT)
{
    int b = blockIdx.x;
    int t = threadIdx.x;
    if (b < CAST_BLOCKS) {
        int i = b * 256 + t;
        float4 v = reinterpret_cast<const float4*>(x)[i];
        ushort4 h;
        h.x = f2b(v.x); h.y = f2b(v.y); h.z = f2b(v.z); h.w = f2b(v.w);
        reinterpret_cast<ushort4*>(xh)[i] = h;
    } else {
        int idx = (b - CAST_BLOCKS) * 256 + t;    // k*128+n over [128][128]
        int n = idx & 127;
        int k = idx >> 7;
        WhT[n * 256 + k]       = f2b(Wl[idx]);
        WhT[n * 256 + 128 + k] = f2b(Wr[idx]);
    }
}

// ---------------- binA: block-local counting sort into global bucket runs ------
__global__ __launch_bounds__(256) void binA_kernel(
    const int* __restrict__ src, const int* __restrict__ dst,
    int* __restrict__ gcur, unsigned int* __restrict__ buf)
{
    __shared__ unsigned int img[EPB];        // 16 KB block-sorted image
    __shared__ int hist[NBUCK];              // counts, then rank cursors
    __shared__ int lbase[NBUCK];             // exclusive prefix within block
    __shared__ int gbase[NBUCK];             // global target of this block's run
    const int tid = threadIdx.x;
    const int e0 = blockIdx.x * EPB;
    const int n = min(EPB, N_EDGES - e0);

    for (int i = tid; i < NBUCK; i += 256) hist[i] = 0;
    __syncthreads();
    for (int i = tid; i < n; i += 256)
        atomicAdd(&hist[dst[e0 + i] >> 6], 1);
    __syncthreads();
    // exclusive scan of hist[0..781]: wave 0, 13 values per lane
    if (tid < 64) {
        int c0 = tid * 13;
        int v[13];
        int s = 0;
        #pragma unroll
        for (int j = 0; j < 13; ++j) {
            int idx = c0 + j;
            v[j] = (idx < NBUCK) ? hist[idx] : 0;
            s += v[j];
        }
        int incl = s;
        #pragma unroll
        for (int d = 1; d < 64; d <<= 1) {
            int t = __shfl_up(incl, d, 64);
            if (tid >= d) incl += t;
        }
        int run = incl - s;
        #pragma unroll
        for (int j = 0; j < 13; ++j) {
            int idx = c0 + j;
            if (idx < NBUCK) lbase[idx] = run;
            run += v[j];
        }
    }
    __syncthreads();
    for (int i = tid; i < NBUCK; i += 256) {
        int c = hist[i];
        gbase[i] = i * SLACK + (c ? atomicAdd(&gcur[i], c) : 0);
        hist[i] = 0;                         // reuse as rank cursor
    }
    __syncthreads();
    for (int i = tid; i < n; i += 256) {
        int d = dst[e0 + i];
        int s = src[e0 + i];
        int b = d >> 6;
        int r = atomicAdd(&hist[b], 1);
        img[lbase[b] + r] = (unsigned int)s | ((unsigned int)d << 16);
    }
    __syncthreads();
    for (int i = tid; i < n; i += 256) {
        unsigned int v = img[i];
        int b = (int)(v >> 16) >> 6;
        int pos = gbase[b] + (i - lbase[b]);
        if (pos < (b + 1) * SLACK) buf[pos] = v;   // overflow drops, not corrupts
    }
}

// ---------------- binBC: LDS CSR + gather-mean + MFMA GEMM + LN + ReLU ---------
// SPLIT blocks per bucket; each gathers a 32-node slice into an LDS bf16 tile,
// then computes the 32x128 output tile (A: LDS agg ++ own xh rows, B: WhT).
__global__ __launch_bounds__(256) void binBC_kernel(
    const unsigned int* __restrict__ buf,
    const int* __restrict__ gcur,
    const unsigned short* __restrict__ xh,
    const unsigned short* __restrict__ WhT,
    const float* __restrict__ bl,
    const float* __restrict__ gamma,
    const float* __restrict__ beta,
    float* __restrict__ out)
{
    __shared__ unsigned int ebuf[SLACK];         // 5,120 B packed edges
    __shared__ unsigned short csr[SLACK];        // 2,560 B local CSR (src u16)
    __shared__ int dhist[BNODES];                // per-node degree
    __shared__ int dbase[BNODES];                // per-node CSR offset
    __shared__ int dcur[BNODES];                 // per-node rank cursor
    __shared__ unsigned short aggh[M_TILE][DIM + 8];  // 8,704 B bf16 agg tile
    __shared__ float sRed[M_TILE][4][2];         // 1,024 B LN partials

    const int tid = threadIdx.x;
    const int w = tid >> 6;
    const int lane = tid & 63;
    const int r16 = lane & 15;
    const int kg = lane >> 4;
    const int b = blockIdx.x / SPLIT;            // bucket
    const int half = blockIdx.x % SPLIT;         // node slice
    const int rb = blockIdx.x * M_TILE;          // global row base
    const int cnt = min(gcur[b], SLACK);
    const unsigned int* bp = buf + (size_t)b * SLACK;

    // ---- local CSR build (bucket-wide, 64 nodes)
    if (tid < BNODES) { dhist[tid] = 0; dcur[tid] = 0; }
    for (int i = tid; i < cnt; i += 256) ebuf[i] = bp[i];
    __syncthreads();
    for (int i = tid; i < cnt; i += 256)
        atomicAdd(&dhist[(ebuf[i] >> 16) & 63], 1);
    __syncthreads();
    if (tid < 64) {                              // scan 64 degree values
        int v = dhist[tid];
        int incl = v;
        #pragma unroll
        for (int d = 1; d < 64; d <<= 1) {
            int t = __shfl_up(incl, d, 64);
            if (tid >= d) incl += t;
        }
        dbase[tid] = incl - v;
    }
    __syncthreads();
    for (int i = tid; i < cnt; i += 256) {
        unsigned int v = ebuf[i];
        int d = (v >> 16) & 63;
        int r = atomicAdd(&dcur[d], 1);
        csr[dbase[d] + r] = (unsigned short)(v & 0xFFFFu);
    }
    __syncthreads();

    // ---- gather-mean into LDS bf16 tile (wave w -> local rows w, w+4, ...)
    const unsigned int* xp = reinterpret_cast<const unsigned int*>(xh);
    for (int j = 0; j < M_TILE / 4; ++j) {
        int lnl = w + 4 * j;                     // 0..31 row in aggh
        int ln = half * M_TILE + lnl;            // 0..63 in bucket
        int node = b * BNODES + ln;
        int deg = (node < N_NODES) ? dhist[ln] : 0;
        int start = dbase[ln];
        float ax = 0.f, ay = 0.f;
        if (deg > 0) {
            int dm1 = deg - 1;
            unsigned int v[16];                  // 16-deep clamped batch
            #pragma unroll
            for (int t = 0; t < 16; ++t)
                v[t] = xp[csr[start + min(t, dm1)] * 64 + lane];
            #pragma unroll
            for (int t = 0; t < 16; ++t)
                if (t < deg) { ax += blo(v[t]); ay += bhi(v[t]); }
            for (int base = 16; base < deg; base += 8) {
                unsigned int u[8];
                #pragma unroll
                for (int t = 0; t < 8; ++t)
                    u[t] = xp[csr[start + min(base + t, dm1)] * 64 + lane];
                #pragma unroll
                for (int t = 0; t < 8; ++t)
                    if (base + t < deg) { ax += blo(u[t]); ay += bhi(u[t]); }
            }
        }
        float inv = 1.0f / (float)max(deg, 1);
        unsigned int pk = (unsigned int)f2b(ax * inv)
                        | ((unsigned int)f2b(ay * inv) << 16);
        *reinterpret_cast<unsigned int*>(&aggh[lnl][lane * 2]) = pk;
    }
    __syncthreads();

    // ---- B preload after gather (keeps VGPR lifetimes disjoint)
    bf16x8 bf[2][8];
    #pragma unroll
    for (int f = 0; f < 2; ++f) {
        const unsigned short* wp = WhT + (w * 32 + f * 16 + r16) * 256 + kg * 8;
        #pragma unroll
        for (int kf = 0; kf < 8; ++kf)
            bf[f][kf] = *reinterpret_cast<const bf16x8*>(wp + kf * 32);
    }

    // ---- MFMA GEMM: 32 rows x 128 cols, K=256
    f32x4 acc[MW][2];
    #pragma unroll
    for (int m = 0; m < MW; ++m)
        #pragma unroll
        for (int f = 0; f < 2; ++f)
            acc[m][f] = (f32x4){0.f, 0.f, 0.f, 0.f};

    #pragma unroll
    for (int kf = 0; kf < 8; ++kf) {
        bf16x8 a[MW];
        if (kf < 4) {
            #pragma unroll
            for (int m = 0; m < MW; ++m)
                a[m] = *reinterpret_cast<const bf16x8*>(
                    &aggh[m * 16 + r16][kf * 32 + kg * 8]);
        } else {
            #pragma unroll
            for (int m = 0; m < MW; ++m)
                a[m] = *reinterpret_cast<const bf16x8*>(
                    xh + (size_t)(rb + m * 16 + r16) * DIM + (kf - 4) * 32 + kg * 8);
        }
        #pragma unroll
        for (int m = 0; m < MW; ++m)
            #pragma unroll
            for (int f = 0; f < 2; ++f)
                acc[m][f] = __builtin_amdgcn_mfma_f32_16x16x32_bf16(
                    a[m], bf[f][kf], acc[m][f], 0, 0, 0);
    }

    // ---- bias + LayerNorm + ReLU epilogue
    float blv[2], gav[2], bev[2];
    #pragma unroll
    for (int f = 0; f < 2; ++f) {
        int col = w * 32 + f * 16 + r16;
        blv[f] = bl[col]; gav[f] = gamma[col]; bev[f] = beta[col];
    }
    #pragma unroll
    for (int m = 0; m < MW; ++m)
        #pragma unroll
        for (int r = 0; r < 4; ++r) {
            float v0 = acc[m][0][r] + blv[0];
            float v1 = acc[m][1][r] + blv[1];
            acc[m][0][r] = v0; acc[m][1][r] = v1;
            float s = v0 + v1;
            float q = v0 * v0 + v1 * v1;
            #pragma unroll
            for (int d = 1; d < 16; d <<= 1) {
                s += __shfl_xor(s, d, 16);
                q += __shfl_xor(q, d, 16);
            }
            if (r16 == 0) {
                sRed[m * 16 + kg * 4 + r][w][0] = s;
                sRed[m * 16 + kg * 4 + r][w][1] = q;
            }
        }
    __syncthreads();

    #pragma unroll
    for (int m = 0; m < MW; ++m)
        #pragma unroll
        for (int r = 0; r < 4; ++r) {
            int lr = m * 16 + kg * 4 + r;
            float S = sRed[lr][0][0] + sRed[lr][1][0] + sRed[lr][2][0] + sRed[lr][3][0];
            float Q = sRed[lr][0][1] + sRed[lr][1][1] + sRed[lr][2][1] + sRed[lr][3][1];
            float mean = S * (1.0f / 128.0f);
            float var = Q * (1.0f / 128.0f) - mean * mean;
            float rstd = rsqrtf(var + 1e-5f);
            int row = rb + lr;
            if (row < N_NODES) {
                #pragma unroll
                for (int f = 0; f < 2; ++f) {
                    float o = (acc[m][f][r] - mean) * rstd * gav[f] + bev[f];
                    out[(size_t)row * DIM + w * 32 + f * 16 + r16] = fmaxf(o, 0.f);
                }
            }
        }
}

extern "C" void kernel_launch(void* const* d_in, const int* in_sizes, int n_in,
                              void* d_out, int out_size, void* d_ws, size_t ws_size,
                              hipStream_t stream) {
    const float* x     = (const float*)d_in[0];
    const int*   ei    = (const int*)d_in[1];
    const float* Wl    = (const float*)d_in[2];
    const float* bl    = (const float*)d_in[3];
    const float* Wr    = (const float*)d_in[4];
    const float* gamma = (const float*)d_in[5];
    const float* beta  = (const float*)d_in[6];
    float* out = (float*)d_out;
    int*           gcur = (int*)d_ws;
    unsigned int*  buf  = (unsigned int*)((char*)d_ws + WS_BUF_OFF);
    unsigned short* xh  = (unsigned short*)((char*)d_ws + WS_XH_OFF);
    unsigned short* WhT = (unsigned short*)((char*)d_ws + WS_WT_OFF);

    const int* src = ei;
    const int* dst = ei + N_EDGES;

    (void)hipMemsetAsync(gcur, 0, 1024 * sizeof(int), stream);

    prep_kernel<<<CAST_BLOCKS + WT_BLOCKS, 256, 0, stream>>>(x, Wl, Wr, xh, WhT);
    binA_kernel<<<NBLKA, 256, 0, stream>>>(src, dst, gcur, buf);
    binBC_kernel<<<NBUCK * SPLIT, 256, 0, stream>>>(
        buf, gcur, xh, WhT, bl, gamma, beta, out);
}

// Round 11
// 78.449 us; speedup vs baseline: 1.3410x; 1.1943x over previous
//
#include <hip/hip_runtime.h>

#define N_NODES 50000
#define N_EDGES 800000
#define DIM 128
#define M_PAD 50048                 // 1564 binBC blocks * 32 rows

#define BNODES 64                   // nodes per bucket (dst>>6)
#define NBUCK 782                   // ceil(N_NODES / 64)
#define SLACK 1280                  // per-bucket capacity (mean 1023, sigma 32)
#define EPB   4096                  // edges per binA block
#define NBLKA ((N_EDGES + EPB - 1) / EPB)   // 196
#define SPLIT 2                     // binBC blocks per bucket

#define M_TILE 32                   // binBC: rows per block
#define MW 2                        // binBC: 16-row m-frags per wave

typedef __attribute__((ext_vector_type(8))) short bf16x8;
typedef __attribute__((ext_vector_type(4))) float f32x4;

// ws layout (bytes):
//   int gcur[1024]                    @ 0            (4,096)
//   u32 buf[NBUCK*SLACK]              @ 4,096        (4,003,840)
//   bf16 xh[M_PAD][128]               @ 4,007,936    (12,812,288)
//   bf16 WhT[128][256]                @ 16,820,224   (65,536)   -> total 16.9 MB
#define WS_BUF_OFF 4096
#define WS_XH_OFF  (WS_BUF_OFF + (size_t)NBUCK * SLACK * 4)
#define WS_WT_OFF  (WS_XH_OFF + (size_t)M_PAD * DIM * 2)

static __device__ __forceinline__ unsigned short f2b(float f) {
    unsigned int x = __float_as_uint(f);
    x += 0x7fffu + ((x >> 16) & 1u);
    return (unsigned short)(x >> 16);
}
static __device__ __forceinline__ float blo(unsigned int v) {
    return __uint_as_float(v << 16);
}
static __device__ __forceinline__ float bhi(unsigned int v) {
    return __uint_as_float(v & 0xffff0000u);
}

// ---------------- prepA: binA (blocks 0..195, starts first) + cast + WhT -------
#define CAST_BLOCKS 6250            // 6.4M floats / 4 / 256
#define WT_BLOCKS 64

__global__ __launch_bounds__(256) void prepA_kernel(
    const float* __restrict__ x,
    const float* __restrict__ Wl,
    const float* __restrict__ Wr,
    const int* __restrict__ src,
    const int* __restrict__ dst,
    unsigned short* __restrict__ xh,
    unsigned short* __restrict__ WhT,
    int* __restrict__ gcur,
    unsigned int* __restrict__ buf)
{
    __shared__ unsigned int img[EPB];        // 16 KB (binA blocks only)
    __shared__ int hist[NBUCK];
    __shared__ int lbase[NBUCK];
    __shared__ int gbase[NBUCK];

    const int blk = blockIdx.x;
    const int tid = threadIdx.x;

    if (blk >= NBLKA) {
        int b = blk - NBLKA;
        if (b < CAST_BLOCKS) {               // cast x -> bf16
            int i = b * 256 + tid;
            float4 v = reinterpret_cast<const float4*>(x)[i];
            ushort4 h;
            h.x = f2b(v.x); h.y = f2b(v.y); h.z = f2b(v.z); h.w = f2b(v.w);
            reinterpret_cast<ushort4*>(xh)[i] = h;
        } else {                             // build WhT
            int idx = (b - CAST_BLOCKS) * 256 + tid;   // k*128+n over [128][128]
            int n = idx & 127;
            int k = idx >> 7;
            WhT[n * 256 + k]       = f2b(Wl[idx]);
            WhT[n * 256 + 128 + k] = f2b(Wr[idx]);
        }
        return;
    }

    // ---- binA: block-local counting sort into global bucket runs
    const int e0 = blk * EPB;
    const int n = min(EPB, N_EDGES - e0);

    for (int i = tid; i < NBUCK; i += 256) hist[i] = 0;
    __syncthreads();
    for (int i = tid; i < n; i += 256)
        atomicAdd(&hist[dst[e0 + i] >> 6], 1);
    __syncthreads();
    if (tid < 64) {                          // excl. scan of hist[0..781]
        int c0 = tid * 13;
        int v[13];
        int s = 0;
        #pragma unroll
        for (int j = 0; j < 13; ++j) {
            int idx = c0 + j;
            v[j] = (idx < NBUCK) ? hist[idx] : 0;
            s += v[j];
        }
        int incl = s;
        #pragma unroll
        for (int d = 1; d < 64; d <<= 1) {
            int t = __shfl_up(incl, d, 64);
            if (tid >= d) incl += t;
        }
        int run = incl - s;
        #pragma unroll
        for (int j = 0; j < 13; ++j) {
            int idx = c0 + j;
            if (idx < NBUCK) lbase[idx] = run;
            run += v[j];
        }
    }
    __syncthreads();
    for (int i = tid; i < NBUCK; i += 256) {
        int c = hist[i];
        gbase[i] = i * SLACK + (c ? atomicAdd(&gcur[i], c) : 0);
        hist[i] = 0;                         // reuse as rank cursor
    }
    __syncthreads();
    for (int i = tid; i < n; i += 256) {
        int d = dst[e0 + i];
        int s = src[e0 + i];
        int b = d >> 6;
        int r = atomicAdd(&hist[b], 1);
        img[lbase[b] + r] = (unsigned int)s | ((unsigned int)d << 16);
    }
    __syncthreads();
    for (int i = tid; i < n; i += 256) {
        unsigned int v = img[i];
        int b = (int)(v >> 16) >> 6;
        int pos = gbase[b] + (i - lbase[b]);
        if (pos < (b + 1) * SLACK) buf[pos] = v;   // overflow drops, not corrupts
    }
}

// ---------------- binBC: LDS CSR + pair-gather-mean + MFMA GEMM + LN + ReLU ----
__global__ __launch_bounds__(256) void binBC_kernel(
    const unsigned int* __restrict__ buf,
    const int* __restrict__ gcur,
    const unsigned short* __restrict__ xh,
    const unsigned short* __restrict__ WhT,
    const float* __restrict__ bl,
    const float* __restrict__ gamma,
    const float* __restrict__ beta,
    float* __restrict__ out)
{
    __shared__ unsigned int ebuf[SLACK];              // 5,120 B packed edges
    __shared__ unsigned short csr[SLACK + 16];        // 2,592 B local CSR, zeroed
    __shared__ int dhist[BNODES];
    __shared__ int dbase[BNODES];
    __shared__ int dcur[BNODES];
    __shared__ unsigned short aggh[M_TILE][DIM + 8];  // 8,704 B bf16 agg tile
    __shared__ float sRed[M_TILE][4][2];              // 1,024 B LN partials

    const int tid = threadIdx.x;
    const int w = tid >> 6;
    const int lane = tid & 63;
    const int r16 = lane & 15;
    const int kg = lane >> 4;
    const int b = blockIdx.x / SPLIT;            // bucket
    const int half = blockIdx.x % SPLIT;         // node slice
    const int rb = blockIdx.x * M_TILE;          // global row base
    const int cnt = min(gcur[b], SLACK);
    const unsigned int* bp = buf + (size_t)b * SLACK;

    // ---- local CSR build (bucket-wide, 64 nodes); csr zero-init for safe clamp
    if (tid < BNODES) { dhist[tid] = 0; dcur[tid] = 0; }
    for (int i = tid; i < (SLACK + 16) / 2; i += 256)
        reinterpret_cast<unsigned int*>(csr)[i] = 0;
    for (int i = tid; i < cnt; i += 256) ebuf[i] = bp[i];
    __syncthreads();
    for (int i = tid; i < cnt; i += 256)
        atomicAdd(&dhist[(ebuf[i] >> 16) & 63], 1);
    __syncthreads();
    if (tid < 64) {                              // scan 64 degree values
        int v = dhist[tid];
        int incl = v;
        #pragma unroll
        for (int d = 1; d < 64; d <<= 1) {
            int t = __shfl_up(incl, d, 64);
            if (tid >= d) incl += t;
        }
        dbase[tid] = incl - v;
    }
    __syncthreads();
    for (int i = tid; i < cnt; i += 256) {
        unsigned int v = ebuf[i];
        int d = (v >> 16) & 63;
        int r = atomicAdd(&dcur[d], 1);
        csr[dbase[d] + r] = (unsigned short)(v & 0xFFFFu);
    }
    __syncthreads();

    // ---- pair-gather: wave w does rows {w+8j, w+8j+4}; 32 loads in flight
    const unsigned int* xp = reinterpret_cast<const unsigned int*>(xh);
    for (int j = 0; j < M_TILE / 8; ++j) {
        int lnlA = w + 8 * j;
        int lnlB = lnlA + 4;
        int lnA = half * M_TILE + lnlA;
        int lnB = half * M_TILE + lnlB;
        int nodeA = b * BNODES + lnA;
        int nodeB = b * BNODES + lnB;
        int degA = (nodeA < N_NODES) ? dhist[lnA] : 0;
        int degB = (nodeB < N_NODES) ? dhist[lnB] : 0;
        int stA = dbase[lnA], stB = dbase[lnB];
        int dmA = max(degA - 1, 0), dmB = max(degB - 1, 0);
        float axA = 0.f, ayA = 0.f, axB = 0.f, ayB = 0.f;

        unsigned int vA[16], vB[16];
        #pragma unroll
        for (int t = 0; t < 16; ++t)
            vA[t] = xp[csr[stA + min(t, dmA)] * 64 + lane];
        #pragma unroll
        for (int t = 0; t < 16; ++t)
            vB[t] = xp[csr[stB + min(t, dmB)] * 64 + lane];
        #pragma unroll
        for (int t = 0; t < 16; ++t) {
            if (t < degA) { axA += blo(vA[t]); ayA += bhi(vA[t]); }
            if (t < degB) { axB += blo(vB[t]); ayB += bhi(vB[t]); }
        }
        for (int base = 16; base < degA; base += 8) {
            unsigned int u[8];
            #pragma unroll
            for (int t = 0; t < 8; ++t)
                u[t] = xp[csr[stA + min(base + t, dmA)] * 64 + lane];
            #pragma unroll
            for (int t = 0; t < 8; ++t)
                if (base + t < degA) { axA += blo(u[t]); ayA += bhi(u[t]); }
        }
        for (int base = 16; base < degB; base += 8) {
            unsigned int u[8];
            #pragma unroll
            for (int t = 0; t < 8; ++t)
                u[t] = xp[csr[stB + min(base + t, dmB)] * 64 + lane];
            #pragma unroll
            for (int t = 0; t < 8; ++t)
                if (base + t < degB) { axB += blo(u[t]); ayB += bhi(u[t]); }
        }
        float invA = 1.0f / (float)max(degA, 1);
        float invB = 1.0f / (float)max(degB, 1);
        unsigned int pkA = (unsigned int)f2b(axA * invA)
                         | ((unsigned int)f2b(ayA * invA) << 16);
        unsigned int pkB = (unsigned int)f2b(axB * invB)
                         | ((unsigned int)f2b(ayB * invB) << 16);
        *reinterpret_cast<unsigned int*>(&aggh[lnlA][lane * 2]) = pkA;
        *reinterpret_cast<unsigned int*>(&aggh[lnlB][lane * 2]) = pkB;
    }
    __syncthreads();

    // ---- MFMA GEMM: 32 rows x 128 cols, K=256 (A: LDS agg ++ own xh rows)
    f32x4 acc[MW][2];
    #pragma unroll
    for (int m = 0; m < MW; ++m)
        #pragma unroll
        for (int f = 0; f < 2; ++f)
            acc[m][f] = (f32x4){0.f, 0.f, 0.f, 0.f};

    #pragma unroll
    for (int kf = 0; kf < 8; ++kf) {
        bf16x8 a[MW];
        bf16x8 bfk[2];
        #pragma unroll
        for (int f = 0; f < 2; ++f)
            bfk[f] = *reinterpret_cast<const bf16x8*>(
                WhT + (w * 32 + f * 16 + r16) * 256 + kf * 32 + kg * 8);
        if (kf < 4) {
            #pragma unroll
            for (int m = 0; m < MW; ++m)
                a[m] = *reinterpret_cast<const bf16x8*>(
                    &aggh[m * 16 + r16][kf * 32 + kg * 8]);
        } else {
            #pragma unroll
            for (int m = 0; m < MW; ++m)
                a[m] = *reinterpret_cast<const bf16x8*>(
                    xh + (size_t)(rb + m * 16 + r16) * DIM + (kf - 4) * 32 + kg * 8);
        }
        #pragma unroll
        for (int m = 0; m < MW; ++m)
            #pragma unroll
            for (int f = 0; f < 2; ++f)
                acc[m][f] = __builtin_amdgcn_mfma_f32_16x16x32_bf16(
                    a[m], bfk[f], acc[m][f], 0, 0, 0);
    }

    // ---- bias + LayerNorm + ReLU epilogue
    float blv[2], gav[2], bev[2];
    #pragma unroll
    for (int f = 0; f < 2; ++f) {
        int col = w * 32 + f * 16 + r16;
        blv[f] = bl[col]; gav[f] = gamma[col]; bev[f] = beta[col];
    }
    #pragma unroll
    for (int m = 0; m < MW; ++m)
        #pragma unroll
        for (int r = 0; r < 4; ++r) {
            float v0 = acc[m][0][r] + blv[0];
            float v1 = acc[m][1][r] + blv[1];
            acc[m][0][r] = v0; acc[m][1][r] = v1;
            float s = v0 + v1;
            float q = v0 * v0 + v1 * v1;
            #pragma unroll
            for (int d = 1; d < 16; d <<= 1) {
                s += __shfl_xor(s, d, 16);
                q += __shfl_xor(q, d, 16);
            }
            if (r16 == 0) {
                sRed[m * 16 + kg * 4 + r][w][0] = s;
                sRed[m * 16 + kg * 4 + r][w][1] = q;
            }
        }
    __syncthreads();

    #pragma unroll
    for (int m = 0; m < MW; ++m)
        #pragma unroll
        for (int r = 0; r < 4; ++r) {
            int lr = m * 16 + kg * 4 + r;
            float S = sRed[lr][0][0] + sRed[lr][1][0] + sRed[lr][2][0] + sRed[lr][3][0];
            float Q = sRed[lr][0][1] + sRed[lr][1][1] + sRed[lr][2][1] + sRed[lr][3][1];
            float mean = S * (1.0f / 128.0f);
            float var = Q * (1.0f / 128.0f) - mean * mean;
            float rstd = rsqrtf(var + 1e-5f);
            int row = rb + lr;
            if (row < N_NODES) {
                #pragma unroll
                for (int f = 0; f < 2; ++f) {
                    float o = (acc[m][f][r] - mean) * rstd * gav[f] + bev[f];
                    out[(size_t)row * DIM + w * 32 + f * 16 + r16] = fmaxf(o, 0.f);
                }
            }
        }
}

extern "C" void kernel_launch(void* const* d_in, const int* in_sizes, int n_in,
                              void* d_out, int out_size, void* d_ws, size_t ws_size,
                              hipStream_t stream) {
    const float* x     = (const float*)d_in[0];
    const int*   ei    = (const int*)d_in[1];
    const float* Wl    = (const float*)d_in[2];
    const float* bl    = (const float*)d_in[3];
    const float* Wr    = (const float*)d_in[4];
    const float* gamma = (const float*)d_in[5];
    const float* beta  = (const float*)d_in[6];
    float* out = (float*)d_out;
    int*           gcur = (int*)d_ws;
    unsigned int*  buf  = (unsigned int*)((char*)d_ws + WS_BUF_OFF);
    unsigned short* xh  = (unsigned short*)((char*)d_ws + WS_XH_OFF);
    unsigned short* WhT = (unsigned short*)((char*)d_ws + WS_WT_OFF);

    const int* src = ei;
    const int* dst = ei + N_EDGES;

    (void)hipMemsetAsync(gcur, 0, 1024 * sizeof(int), stream);

    prepA_kernel<<<NBLKA + CAST_BLOCKS + WT_BLOCKS, 256, 0, stream>>>(
        x, Wl, Wr, src, dst, xh, WhT, gcur, buf);
    binBC_kernel<<<NBUCK * SPLIT, 256, 0, stream>>>(
        buf, gcur, xh, WhT, bl, gamma, beta, out);
}